// Round 5
// baseline (165.169 us; speedup 1.0000x reference)
//
#include <hip/hip_runtime.h>
#include <math.h>

#define BB   256   // batch
#define OBS  256
#define HH   1024
#define AA   18

// clang-native packed f16: + -> v_pk_add_f16, elementwise_max -> v_pk_max_f16
typedef _Float16 h2 __attribute__((ext_vector_type(2)));
typedef _Float16 f16x8 __attribute__((ext_vector_type(8)));
typedef float f32x4 __attribute__((ext_vector_type(4)));

static __device__ __forceinline__ h2 u2h(unsigned int u) {
  return __builtin_bit_cast(h2, u);
}
static __device__ __forceinline__ unsigned int h2u(h2 v) {
  return __builtin_bit_cast(unsigned int, v);
}
// v_cvt_pkrtz_f16_f32: two f32 -> packed f16 dword (builtin returns __fp16x2)
static __device__ __forceinline__ unsigned int pkrtz(float a, float b) {
  return __builtin_bit_cast(unsigned int, __builtin_amdgcn_cvt_pkrtz(a, b));
}

// ---------------------------------------------------------------------------
// fc_in (MFMA): h1pk[o/2][b] = pack_f16( x@W_in^T + b_in )   [R2-verified]
// ---------------------------------------------------------------------------
__global__ __launch_bounds__(256) void fc_in_kernel(
    const float* __restrict__ x, const float* __restrict__ Wi,
    const float* __restrict__ bi, unsigned int* __restrict__ h1pk) {
  const int t    = threadIdx.x;
  const int lane = t & 63;
  const int wid  = blockIdx.x * 4 + (t >> 6);   // 0..1023
  const int ot   = wid >> 4;                    // 0..63  (16 o rows)
  const int bt   = wid & 15;                    // 0..15  (16 b cols)
  const int r    = lane & 15;
  const int g    = lane >> 4;                   // 0..3

  const float* __restrict__ wrow = Wi + (size_t)(ot * 16 + r) * OBS + g * 8;
  const float* __restrict__ xrow = x  + (size_t)(bt * 16 + r) * OBS + g * 8;

  f32x4 acc = {0.f, 0.f, 0.f, 0.f};
#pragma unroll
  for (int ks = 0; ks < 8; ++ks) {
    const float4 wa = *(const float4*)(wrow + ks * 32);
    const float4 wb = *(const float4*)(wrow + ks * 32 + 4);
    const float4 xa = *(const float4*)(xrow + ks * 32);
    const float4 xb = *(const float4*)(xrow + ks * 32 + 4);
    const uint4 au = make_uint4(pkrtz(wa.x, wa.y), pkrtz(wa.z, wa.w),
                                pkrtz(wb.x, wb.y), pkrtz(wb.z, wb.w));
    const uint4 bu = make_uint4(pkrtz(xa.x, xa.y), pkrtz(xa.z, xa.w),
                                pkrtz(xb.x, xb.y), pkrtz(xb.z, xb.w));
    acc = __builtin_amdgcn_mfma_f32_16x16x32_f16(
        __builtin_bit_cast(f16x8, au), __builtin_bit_cast(f16x8, bu),
        acc, 0, 0, 0);
  }

  const int o0 = ot * 16 + g * 4;
  const float4 b4 = *(const float4*)(bi + o0);
  const h2 p0 = {(_Float16)(acc[0] + b4.x), (_Float16)(acc[1] + b4.y)};
  const h2 p1 = {(_Float16)(acc[2] + b4.z), (_Float16)(acc[3] + b4.w)};
  const int col = bt * 16 + r;
  h1pk[(size_t)(ot * 8 + g * 2) * BB + col]     = h2u(p0);
  h1pk[(size_t)(ot * 8 + g * 2 + 1) * BB + col] = h2u(p1);
}

// ---------------------------------------------------------------------------
// mmplus v3 + DIAGNOSTIC `reps` argument: the whole body (stage W -> main
// loop -> reduce -> store) repeats `reps` times. Idempotent: inputs are
// unchanged, every rep recomputes and rewrites identical outputs. Purpose:
// with reps=6 the dispatch exceeds the 41us harness fills and surfaces in
// the rocprof top-5 with true per-kernel counters (we've never seen them).
// Runtime trip count + per-rep barrier + memory clobber prevent the
// compiler from collapsing reps (rule #17).
// ---------------------------------------------------------------------------
template <bool IS_MAX>
static __device__ __forceinline__ void mm_iter(h2 (&acc)[2][4],
                                               const uint4& he, const uint4& ho,
                                               const uint2& w0, const uint2& w1) {
  const h2 h0v[4] = {u2h(he.x), u2h(he.y), u2h(he.z), u2h(he.w)};
  const h2 h1v[4] = {u2h(ho.x), u2h(ho.y), u2h(ho.z), u2h(ho.w)};
  const h2 wa[2] = {u2h(w0.x), u2h(w1.x)};
  const h2 wb[2] = {u2h(w0.y), u2h(w1.y)};
#pragma unroll
  for (int j = 0; j < 2; ++j) {
#pragma unroll
    for (int bb = 0; bb < 4; ++bb) {
      if (IS_MAX) {
        acc[j][bb] = __builtin_elementwise_max(acc[j][bb], wa[j] + h0v[bb]);
        acc[j][bb] = __builtin_elementwise_max(acc[j][bb], wb[j] + h1v[bb]);
      } else {
        acc[j][bb] = __builtin_elementwise_min(acc[j][bb], wa[j] + h0v[bb]);
        acc[j][bb] = __builtin_elementwise_min(acc[j][bb], wb[j] + h1v[bb]);
      }
    }
  }
}

template <bool IS_MAX>
__global__ __launch_bounds__(1024) void mmplus_kernel(
    const unsigned int* __restrict__ hpk,   // [H/2][B] dwords (i-pair, b)
    const float* __restrict__ Wf,           // [H][H] f32 (o, i)
    unsigned int* __restrict__ opk,         // [H/2][B]
    int reps) {
  constexpr int PITCH = 514;
  __shared__ __align__(16) unsigned int lds[8 * PITCH];  // 16.4 KB; red aliases
  const int t    = threadIdx.x;
  const int lane = t & 63;
  const int og2  = lane >> 4;      // o-pair group 0..3
  const int bq   = lane & 15;      // b-quad 0..15
  const int s    = __builtin_amdgcn_readfirstlane(t >> 6);  // i-split 0..15
  const int og   = blockIdx.x;     // 0..127, 8 o each
  const int bg   = blockIdx.y;

  const unsigned int* __restrict__ hp =
      hpk + (size_t)(s * 32) * BB + bg * 64 + bq * 4;
  const unsigned int* __restrict__ wl = &lds[(og2 * 2) * PITCH + s * 32];
  const _Float16 INIT = (_Float16)(IS_MAX ? -65504.f : 65504.f);

#pragma unroll 1
  for (int rep = 0; rep < reps; ++rep) {
    __syncthreads();   // protect lds (red/wtile alias) from previous rep
    asm volatile("" ::: "memory");

    // ---- stage W tile: 8 rows (two waves per row), f32 -> pk f16 ----
    {
      const int o_l = t >> 7;        // 0..7
      const int c   = t & 127;
      const float4* src = (const float4*)(Wf + (size_t)(og * 8 + o_l) * HH);
      unsigned int* dst = &lds[o_l * PITCH];
#pragma unroll
      for (int k = 0; k < 2; ++k) {
        const float4 v = src[c + 128 * k];
        *(uint2*)&dst[(c + 128 * k) * 2] =
            make_uint2(pkrtz(v.x, v.y), pkrtz(v.z, v.w));
      }
    }
    __syncthreads();

    h2 acc[2][4];
#pragma unroll
    for (int j = 0; j < 2; ++j)
#pragma unroll
      for (int bb = 0; bb < 4; ++bb) acc[j][bb] = (h2){INIT, INIT};

#define LDH(p) (*(const uint4*)(hp + (size_t)(p) * BB))
#define LDW(j, p) (*(const uint2*)(wl + (j) * PITCH + (p)))
    uint4 hA0 = LDH(0), hA1 = LDH(1), hA2 = LDH(2), hA3 = LDH(3);
    uint2 wA00 = LDW(0, 0), wA01 = LDW(0, 2);
    uint2 wA10 = LDW(1, 0), wA11 = LDW(1, 2);

#pragma unroll
    for (int c = 0; c < 8; ++c) {
      uint4 hB0, hB1, hB2, hB3;
      uint2 wB00, wB01, wB10, wB11;
      if (c < 7) {                       // compile-time after full unroll
        const int p = 4 * (c + 1);
        hB0 = LDH(p);     hB1 = LDH(p + 1);
        hB2 = LDH(p + 2); hB3 = LDH(p + 3);
        wB00 = LDW(0, p); wB01 = LDW(0, p + 2);
        wB10 = LDW(1, p); wB11 = LDW(1, p + 2);
      }
      mm_iter<IS_MAX>(acc, hA0, hA1, wA00, wA10);
      mm_iter<IS_MAX>(acc, hA2, hA3, wA01, wA11);
      if (c < 7) {
        hA0 = hB0; hA1 = hB1; hA2 = hB2; hA3 = hB3;
        wA00 = wB00; wA01 = wB01; wA10 = wB10; wA11 = wB11;
      }
    }
#undef LDH
#undef LDW

    // fold even/odd i-partials -> scalar f16 per (o,b); pack o-pair
    unsigned int opack[4];
#pragma unroll
    for (int bb = 0; bb < 4; ++bb) {
      const h2 ae = acc[0][bb], ao = acc[1][bb];
      const _Float16 me = IS_MAX ? (ae.x > ae.y ? ae.x : ae.y)
                                 : (ae.x < ae.y ? ae.x : ae.y);
      const _Float16 mo = IS_MAX ? (ao.x > ao.y ? ao.x : ao.y)
                                 : (ao.x < ao.y ? ao.x : ao.y);
      opack[bb] = h2u((h2){me, mo});
    }

    __syncthreads();  // W reads done; reuse lds[] as red[16][4][64]
#pragma unroll
    for (int bb = 0; bb < 4; ++bb)
      lds[s * 256 + og2 * 64 + bq * 4 + bb] = opack[bb];
    __syncthreads();

    if (t < 256) {
      const int op = t >> 6;   // o-pair 0..3
      const int bl = t & 63;
      h2 m = u2h(lds[op * 64 + bl]);
#pragma unroll
      for (int ks = 1; ks < 16; ++ks) {
        const h2 v = u2h(lds[ks * 256 + op * 64 + bl]);
        m = IS_MAX ? __builtin_elementwise_max(m, v)
                   : __builtin_elementwise_min(m, v);
      }
      opk[(size_t)(og * 4 + op) * BB + bg * 64 + bl] = h2u(m);
    }
  }
}

// ---------------------------------------------------------------------------
// fc_out: q[b][a] = bo[a] + dot(h3[:,b], W_out[a,:])
// ---------------------------------------------------------------------------
__global__ __launch_bounds__(1024) void fc_out_kernel(
    const unsigned int* __restrict__ h3pk, const float* __restrict__ Wo,
    const float* __restrict__ bo, float* __restrict__ q) {
  __shared__ float red[16][64];
  const int a  = blockIdx.x;
  const int bg = blockIdx.y;
  const int t  = threadIdx.x;
  const int bl = t & 63;
  const int ks = __builtin_amdgcn_readfirstlane(t >> 6);  // 0..15

  const unsigned int* __restrict__ hp =
      h3pk + (size_t)(ks * 32) * BB + bg * 64 + bl;
  const float* __restrict__ w = Wo + (size_t)a * HH + ks * 64;

  float acc = 0.f;
#pragma unroll 8
  for (int d = 0; d < 32; ++d) {
    const h2 hv = u2h(hp[(size_t)d * BB]);
    acc = fmaf((float)hv.x, w[2 * d], acc);
    acc = fmaf((float)hv.y, w[2 * d + 1], acc);
  }
  red[ks][bl] = acc;
  __syncthreads();

  if (t < 64) {
    float m = bo[a];
#pragma unroll
    for (int ks2 = 0; ks2 < 16; ++ks2) m += red[ks2][t];
    q[(size_t)(bg * 64 + t) * AA + a] = m;
  }
}

// ---------------------------------------------------------------------------
extern "C" void kernel_launch(void* const* d_in, const int* in_sizes, int n_in,
                              void* d_out, int out_size, void* d_ws, size_t ws_size,
                              hipStream_t stream) {
  const float* x    = (const float*)d_in[0];
  const float* Wi   = (const float*)d_in[1];
  const float* bi   = (const float*)d_in[2];
  const float* Wmax = (const float*)d_in[3];
  const float* Wmin = (const float*)d_in[4];
  const float* Wo   = (const float*)d_in[5];
  const float* bo   = (const float*)d_in[6];
  float* q = (float*)d_out;

  char* ws = (char*)d_ws;
  unsigned int* h1pk = (unsigned int*)ws;  ws += (size_t)(HH / 2) * BB * 4;  // 512 KB
  unsigned int* h2pk = (unsigned int*)ws;  ws += (size_t)(HH / 2) * BB * 4;
  unsigned int* h3pk = (unsigned int*)ws;

  fc_in_kernel<<<dim3(256), 256, 0, stream>>>(x, Wi, bi, h1pk);
  // DIAGNOSTIC: reps=6 makes this dispatch ~6x its true duration so it
  // surfaces in the rocprof top-5 (fills are 41us). Output is identical.
  mmplus_kernel<true ><<<dim3(HH / 8, BB / 64), 1024, 0, stream>>>(h1pk, Wmax, h2pk, 6);
  mmplus_kernel<false><<<dim3(HH / 8, BB / 64), 1024, 0, stream>>>(h2pk, Wmin, h3pk, 1);
  fc_out_kernel<<<dim3(AA, BB / 64), 1024, 0, stream>>>(h3pk, Wo, bo, q);
}

// Round 6
// 101.530 us; speedup vs baseline: 1.6268x; 1.6268x over previous
//
#include <hip/hip_runtime.h>
#include <math.h>

#define BB   256   // batch
#define OBS  256
#define HH   1024
#define AA   18

// clang-native packed f16: + -> v_pk_add_f16, elementwise_max -> v_pk_max_f16
typedef _Float16 h2 __attribute__((ext_vector_type(2)));
typedef _Float16 f16x8 __attribute__((ext_vector_type(8)));
typedef float f32x4 __attribute__((ext_vector_type(4)));

static __device__ __forceinline__ h2 u2h(unsigned int u) {
  return __builtin_bit_cast(h2, u);
}
static __device__ __forceinline__ unsigned int h2u(h2 v) {
  return __builtin_bit_cast(unsigned int, v);
}
// v_cvt_pkrtz_f16_f32: two f32 -> packed f16 dword (builtin returns __fp16x2)
static __device__ __forceinline__ unsigned int pkrtz(float a, float b) {
  return __builtin_bit_cast(unsigned int, __builtin_amdgcn_cvt_pkrtz(a, b));
}

// ---------------------------------------------------------------------------
// fc_in (MFMA): h1pk[o/2][b] = pack_f16( x@W_in^T + b_in )   [R2-verified]
// ---------------------------------------------------------------------------
__global__ __launch_bounds__(256) void fc_in_kernel(
    const float* __restrict__ x, const float* __restrict__ Wi,
    const float* __restrict__ bi, unsigned int* __restrict__ h1pk) {
  const int t    = threadIdx.x;
  const int lane = t & 63;
  const int wid  = blockIdx.x * 4 + (t >> 6);   // 0..1023
  const int ot   = wid >> 4;                    // 0..63  (16 o rows)
  const int bt   = wid & 15;                    // 0..15  (16 b cols)
  const int r    = lane & 15;
  const int g    = lane >> 4;                   // 0..3

  const float* __restrict__ wrow = Wi + (size_t)(ot * 16 + r) * OBS + g * 8;
  const float* __restrict__ xrow = x  + (size_t)(bt * 16 + r) * OBS + g * 8;

  f32x4 acc = {0.f, 0.f, 0.f, 0.f};
#pragma unroll
  for (int ks = 0; ks < 8; ++ks) {
    const float4 wa = *(const float4*)(wrow + ks * 32);
    const float4 wb = *(const float4*)(wrow + ks * 32 + 4);
    const float4 xa = *(const float4*)(xrow + ks * 32);
    const float4 xb = *(const float4*)(xrow + ks * 32 + 4);
    const uint4 au = make_uint4(pkrtz(wa.x, wa.y), pkrtz(wa.z, wa.w),
                                pkrtz(wb.x, wb.y), pkrtz(wb.z, wb.w));
    const uint4 bu = make_uint4(pkrtz(xa.x, xa.y), pkrtz(xa.z, xa.w),
                                pkrtz(xb.x, xb.y), pkrtz(xb.z, xb.w));
    acc = __builtin_amdgcn_mfma_f32_16x16x32_f16(
        __builtin_bit_cast(f16x8, au), __builtin_bit_cast(f16x8, bu),
        acc, 0, 0, 0);
  }

  const int o0 = ot * 16 + g * 4;
  const float4 b4 = *(const float4*)(bi + o0);
  const h2 p0 = {(_Float16)(acc[0] + b4.x), (_Float16)(acc[1] + b4.y)};
  const h2 p1 = {(_Float16)(acc[2] + b4.z), (_Float16)(acc[3] + b4.w)};
  const int col = bt * 16 + r;
  h1pk[(size_t)(ot * 8 + g * 2) * BB + col]     = h2u(p0);
  h1pk[(size_t)(ot * 8 + g * 2 + 1) * BB + col] = h2u(p1);
}

// ---------------------------------------------------------------------------
// mmplus v4 (og-merged): out[o][b] = OP_i( W[o][i] + h[i][b] )
// R5 diagnostics: VALUBusy 53% @ 8 waves/SIMD => ~1000 VALU instr/thread vs
// 512-pk algorithmic floor -- issue-count-bound, not latency-bound. Fix:
// DOUBLE work per thread. Block now covers 16 o x 64 b (grid 256 = 1
// block/CU). Per thread: 4 o-rows x 4 b x 64 i = 1024 pk instr while h
// global loads (32x uint4), addressing, W-stage, reduce, and launch cost
// stay ~constant -> overhead per unit work halves.
// acc[4][4] h2; h double-buffered per chunk (2 iters); W LDS reads
// prefetched 1 iteration ahead (keeps VGPR ~<100, <=128 for 4 waves/SIMD).
// ---------------------------------------------------------------------------
template <bool IS_MAX>
static __device__ __forceinline__ void mm_iter4(h2 (&acc)[4][4],
                                                const uint4& he, const uint4& ho,
                                                const uint2 (&w)[4]) {
  const h2 h0v[4] = {u2h(he.x), u2h(he.y), u2h(he.z), u2h(he.w)};
  const h2 h1v[4] = {u2h(ho.x), u2h(ho.y), u2h(ho.z), u2h(ho.w)};
#pragma unroll
  for (int j = 0; j < 4; ++j) {
    const h2 wa = u2h(w[j].x);
    const h2 wb = u2h(w[j].y);
#pragma unroll
    for (int bb = 0; bb < 4; ++bb) {
      if (IS_MAX) {
        acc[j][bb] = __builtin_elementwise_max(acc[j][bb], wa + h0v[bb]);
        acc[j][bb] = __builtin_elementwise_max(acc[j][bb], wb + h1v[bb]);
      } else {
        acc[j][bb] = __builtin_elementwise_min(acc[j][bb], wa + h0v[bb]);
        acc[j][bb] = __builtin_elementwise_min(acc[j][bb], wb + h1v[bb]);
      }
    }
  }
}

template <bool IS_MAX>
__global__ __launch_bounds__(1024) void mmplus_kernel(
    const unsigned int* __restrict__ hpk,   // [H/2][B] dwords (i-pair, b)
    const float* __restrict__ Wf,           // [H][H] f32 (o, i)
    unsigned int* __restrict__ opk) {       // [H/2][B]
  constexpr int PITCH = 514;  // dwords per o-row (i-pairs, +2 pad)
  __shared__ __align__(16) unsigned int lds[16 * PITCH];  // 32.9 KB; red alias
  const int t    = threadIdx.x;
  const int lane = t & 63;
  const int og2  = lane >> 4;      // o-quad group 0..3 (4 rows each)
  const int bq   = lane & 15;      // b-quad 0..15
  const int s    = __builtin_amdgcn_readfirstlane(t >> 6);  // i-split 0..15
  const int og   = blockIdx.x;     // 0..63, 16 o each
  const int bg   = blockIdx.y;     // 0..3

  // ---- stage W tile: 16 rows, one wave per row, f32 -> pk f16 ----
  {
    const int o_l = t >> 6;        // 0..15 (row)
    const int c   = lane;          // 0..63
    const float4* src = (const float4*)(Wf + (size_t)(og * 16 + o_l) * HH);
    unsigned int* dst = &lds[o_l * PITCH];
#pragma unroll
    for (int k = 0; k < 4; ++k) {
      const float4 v = src[c + 64 * k];
      *(uint2*)&dst[(c + 64 * k) * 2] =
          make_uint2(pkrtz(v.x, v.y), pkrtz(v.z, v.w));
    }
  }
  __syncthreads();

  const unsigned int* __restrict__ hp =
      hpk + (size_t)(s * 32) * BB + bg * 64 + bq * 4;
  const unsigned int* __restrict__ wl = &lds[(og2 * 4) * PITCH + s * 32];

  const _Float16 INIT = (_Float16)(IS_MAX ? -65504.f : 65504.f);
  h2 acc[4][4];
#pragma unroll
  for (int j = 0; j < 4; ++j)
#pragma unroll
    for (int bb = 0; bb < 4; ++bb) acc[j][bb] = (h2){INIT, INIT};

#define LDH(p) (*(const uint4*)(hp + (size_t)(p) * BB))
#define LDW(j, p) (*(const uint2*)(wl + (j) * PITCH + (p)))

  // prologue: h chunk 0 (pairs 0..3), W pairs 0,1 for 4 rows
  uint4 hA0 = LDH(0), hA1 = LDH(1), hA2 = LDH(2), hA3 = LDH(3);
  uint2 wcur[4] = {LDW(0, 0), LDW(1, 0), LDW(2, 0), LDW(3, 0)};

#pragma unroll
  for (int c = 0; c < 8; ++c) {
    uint4 hB0, hB1, hB2, hB3;
    if (c < 7) {                       // compile-time after full unroll
      const int p = 4 * (c + 1);
      hB0 = LDH(p);     hB1 = LDH(p + 1);
      hB2 = LDH(p + 2); hB3 = LDH(p + 3);
    }
    // W prefetch 1 iteration ahead
    uint2 wnext[4] = {LDW(0, 4 * c + 2), LDW(1, 4 * c + 2),
                      LDW(2, 4 * c + 2), LDW(3, 4 * c + 2)};
    mm_iter4<IS_MAX>(acc, hA0, hA1, wcur);       // pairs 4c, 4c+1
    uint2 wnn[4];
    if (c < 7) {
      wnn[0] = LDW(0, 4 * c + 4); wnn[1] = LDW(1, 4 * c + 4);
      wnn[2] = LDW(2, 4 * c + 4); wnn[3] = LDW(3, 4 * c + 4);
    }
    mm_iter4<IS_MAX>(acc, hA2, hA3, wnext);      // pairs 4c+2, 4c+3
    if (c < 7) {
      hA0 = hB0; hA1 = hB1; hA2 = hB2; hA3 = hB3;
      wcur[0] = wnn[0]; wcur[1] = wnn[1]; wcur[2] = wnn[2]; wcur[3] = wnn[3];
    }
  }
#undef LDH
#undef LDW

  // fold even/odd i-partials -> scalar f16 per (o,b); this thread owns
  // block o-rows og2*4+j (j=0..3) = block o-pairs og2*2, og2*2+1.
  unsigned int opack[2][4];
#pragma unroll
  for (int jp = 0; jp < 2; ++jp) {
#pragma unroll
    for (int bb = 0; bb < 4; ++bb) {
      const h2 ae = acc[2 * jp][bb], ao = acc[2 * jp + 1][bb];
      const _Float16 me = IS_MAX ? (ae.x > ae.y ? ae.x : ae.y)
                                 : (ae.x < ae.y ? ae.x : ae.y);
      const _Float16 mo = IS_MAX ? (ao.x > ao.y ? ao.x : ao.y)
                                 : (ao.x < ao.y ? ao.x : ao.y);
      opack[jp][bb] = h2u((h2){me, mo});
    }
  }

  __syncthreads();  // W reads done; reuse lds[] as red[16][8][64] (32 KB)
#pragma unroll
  for (int jp = 0; jp < 2; ++jp)
#pragma unroll
    for (int bb = 0; bb < 4; ++bb)
      lds[s * 512 + (og2 * 2 + jp) * 64 + bq * 4 + bb] = opack[jp][bb];
  __syncthreads();

  if (t < 512) {
    const int op = t >> 6;   // block o-pair 0..7
    const int bl = t & 63;
    h2 m = u2h(lds[op * 64 + bl]);
#pragma unroll
    for (int ks = 1; ks < 16; ++ks) {
      const h2 v = u2h(lds[ks * 512 + op * 64 + bl]);
      m = IS_MAX ? __builtin_elementwise_max(m, v)
                 : __builtin_elementwise_min(m, v);
    }
    opk[(size_t)(og * 8 + op) * BB + bg * 64 + bl] = h2u(m);
  }
}

// ---------------------------------------------------------------------------
// fc_out: q[b][a] = bo[a] + dot(h3[:,b], W_out[a,:])
// ---------------------------------------------------------------------------
__global__ __launch_bounds__(1024) void fc_out_kernel(
    const unsigned int* __restrict__ h3pk, const float* __restrict__ Wo,
    const float* __restrict__ bo, float* __restrict__ q) {
  __shared__ float red[16][64];
  const int a  = blockIdx.x;
  const int bg = blockIdx.y;
  const int t  = threadIdx.x;
  const int bl = t & 63;
  const int ks = __builtin_amdgcn_readfirstlane(t >> 6);  // 0..15

  const unsigned int* __restrict__ hp =
      h3pk + (size_t)(ks * 32) * BB + bg * 64 + bl;
  const float* __restrict__ w = Wo + (size_t)a * HH + ks * 64;

  float acc = 0.f;
#pragma unroll 8
  for (int d = 0; d < 32; ++d) {
    const h2 hv = u2h(hp[(size_t)d * BB]);
    acc = fmaf((float)hv.x, w[2 * d], acc);
    acc = fmaf((float)hv.y, w[2 * d + 1], acc);
  }
  red[ks][bl] = acc;
  __syncthreads();

  if (t < 64) {
    float m = bo[a];
#pragma unroll
    for (int ks2 = 0; ks2 < 16; ++ks2) m += red[ks2][t];
    q[(size_t)(bg * 64 + t) * AA + a] = m;
  }
}

// ---------------------------------------------------------------------------
extern "C" void kernel_launch(void* const* d_in, const int* in_sizes, int n_in,
                              void* d_out, int out_size, void* d_ws, size_t ws_size,
                              hipStream_t stream) {
  const float* x    = (const float*)d_in[0];
  const float* Wi   = (const float*)d_in[1];
  const float* bi   = (const float*)d_in[2];
  const float* Wmax = (const float*)d_in[3];
  const float* Wmin = (const float*)d_in[4];
  const float* Wo   = (const float*)d_in[5];
  const float* bo   = (const float*)d_in[6];
  float* q = (float*)d_out;

  char* ws = (char*)d_ws;
  unsigned int* h1pk = (unsigned int*)ws;  ws += (size_t)(HH / 2) * BB * 4;  // 512 KB
  unsigned int* h2pk = (unsigned int*)ws;  ws += (size_t)(HH / 2) * BB * 4;
  unsigned int* h3pk = (unsigned int*)ws;

  fc_in_kernel<<<dim3(256), 256, 0, stream>>>(x, Wi, bi, h1pk);
  mmplus_kernel<true ><<<dim3(HH / 16, BB / 64), 1024, 0, stream>>>(h1pk, Wmax, h2pk);
  mmplus_kernel<false><<<dim3(HH / 16, BB / 64), 1024, 0, stream>>>(h2pk, Wmin, h3pk);
  fc_out_kernel<<<dim3(AA, BB / 64), 1024, 0, stream>>>(h3pk, Wo, bo, q);
}